// Round 6
// baseline (2198.096 us; speedup 1.0000x reference)
//
#include <hip/hip_runtime.h>
#include <cstddef>

#define NMAT 512
#define MRHS 12

// ---------------- Stage 1: A = LU = constant_part + sum_e r[e] * M[e] ----------------
// 512 blocks x 256 thr; each thread owns exactly one float2 of the 512x512 matrix
// (512*512 floats = 131072 float2 = 512*256 threads) and loops over all 1024 e.
__global__ void __launch_bounds__(256) k_setup(const float* __restrict__ M,
                                               const float* __restrict__ r,
                                               const float* __restrict__ cpart,
                                               float* __restrict__ A,
                                               float* __restrict__ LU) {
    __shared__ float rs[1024];
    const int tid = threadIdx.x;
    for (int i = tid; i < 1024; i += 256) rs[i] = r[i];
    __syncthreads();
    const int idx2 = blockIdx.x * 256 + tid;          // 0..131071
    const float2* __restrict__ M2 = (const float2*)M;
    float2 a = ((const float2*)cpart)[idx2];
    float ax = a.x, ay = a.y;
#pragma unroll 8
    for (int e = 0; e < 1024; ++e) {
        float2 v = M2[(size_t)e * 131072u + idx2];
        float rv = rs[e];
        ax += rv * v.x; ay += rv * v.y;
    }
    float2 o; o.x = ax; o.y = ay;
    ((float2*)A)[idx2] = o;
    ((float2*)LU)[idx2] = o;
}

// ---------------- LU panel factor (no pivoting), NB=64, register-resident ----------------
// 1 block, 1024 threads = 16 waves. Row i of panel lives on wave (i&15), slot (i>>4),
// lane = column. Epilogue writes LU (row-major), the TRANSPOSED panel into LUT
// (rows k0..k1, cols k0..k0+NR), and dinv for the diag block.
template <int NR>
__global__ void __launch_bounds__(1024) k_panel(float* __restrict__ LU,
                                                float* __restrict__ LUT,
                                                float* __restrict__ dinv,
                                                int k0) {
    constexpr int NS = NR / 16;
    __shared__ float piv[2][64];
    __shared__ float T[64 * 65];
    const int tid = threadIdx.x;
    const int w = tid >> 6, lane = tid & 63;
    float reg[NS];
#pragma unroll
    for (int s = 0; s < NS; ++s) {
        int i = s * 16 + w;
        reg[s] = LU[(size_t)(k0 + i) * NMAT + k0 + lane];
    }
    for (int j = 0; j < 64; ++j) {
        if (w == (j & 15)) {
#pragma unroll
            for (int s = 0; s < 4; ++s)
                if ((j >> 4) == s) piv[j & 1][lane] = reg[s];
        }
        __syncthreads();
        float pvl = piv[j & 1][lane];
        float pj = __shfl(pvl, j);
        float pivinv = 1.0f / pj;
#pragma unroll
        for (int s = 0; s < NS; ++s) {
            int i = s * 16 + w;
            if (i > j) {               // wave-uniform branch
                float rv = reg[s];
                float l = __shfl(rv, j) * pivinv;
                float upd = rv - l * pvl;
                rv = (lane > j) ? upd : rv;
                rv = (lane == j) ? l : rv;
                reg[s] = rv;
            }
        }
    }
    // write back LU (row-major) + dinv
#pragma unroll
    for (int s = 0; s < NS; ++s) {
        int i = s * 16 + w;
        LU[(size_t)(k0 + i) * NMAT + k0 + lane] = reg[s];
    }
#pragma unroll
    for (int s = 0; s < 4; ++s)
        if (lane == s * 16 + w) dinv[k0 + lane] = 1.0f / reg[s];
    // transposed panel -> LUT rows k0..k1, cols k0..k0+NR (LDS bounce, 64-row chunks)
    for (int c0 = 0; c0 < NS / 4; ++c0) {
        __syncthreads();
#pragma unroll
        for (int q = 0; q < 4; ++q)
            T[(q * 16 + w) * 65 + lane] = reg[c0 * 4 + q];
        __syncthreads();
#pragma unroll
        for (int q = 0; q < 4; ++q) {
            int j = w * 4 + q;
            LUT[(size_t)(k0 + j) * NMAT + k0 + c0 * 64 + lane] = T[lane * 65 + j];
        }
    }
}

// ---------------- 64x64 forward substitution, register-resident, lane = column -------------
// y starts as the A12 column for this lane; sL holds packed L11 (unit diag implied).
__device__ __forceinline__ void trsm64_reg(float y[64], const float* __restrict__ sL) {
#pragma unroll
    for (int t = 0; t < 63; ++t) {
        float yt = y[t];
#pragma unroll
        for (int i = t + 1; i < 64; ++i)
            y[i] -= sL[i * 68 + t] * yt;   // wave-uniform LDS broadcast
    }
}

// ---------------- fused trsm + trailing update ----------------
// grid (nc/64, nc/64 + 1). EVERY block redundantly computes Ys = L11^{-1} A12 for its
// column tile in registers (stable substitution). A12 in LU is never overwritten ->
// race-free. blockIdx.y == 0: write Ys^T into LUT. blockIdx.y >= 1: A22 -= L21 @ Ys.
__global__ void __launch_bounds__(256) k_update(float* __restrict__ LU,
                                                float* __restrict__ LUT,
                                                int k0) {
    __shared__ float sL[64 * 68];   // L11, then L21
    __shared__ float sY[64 * 68];   // A12 tile, then transpose bounce
    const int k1 = k0 + 64;
    const int jc0 = k1 + blockIdx.x * 64;
    const int tid = threadIdx.x;
    const int w = tid >> 6, lane = tid & 63;
    {
        const int i = tid >> 4, c4 = tid & 15;
        for (int rr = 0; rr < 64; rr += 16) {
            float4 v1 = *(const float4*)&LU[(size_t)(k0 + i + rr) * NMAT + k0 + 4 * c4];
            *(float4*)&sL[(i + rr) * 68 + 4 * c4] = v1;
            float4 v2 = *(const float4*)&LU[(size_t)(k0 + i + rr) * NMAT + jc0 + 4 * c4];
            *(float4*)&sY[(i + rr) * 68 + 4 * c4] = v2;
        }
    }
    __syncthreads();
    float y[64];
#pragma unroll
    for (int i = 0; i < 64; ++i) y[i] = sY[i * 68 + lane];

    if (blockIdx.y == 0) {
        trsm64_reg(y, sL);
        __syncthreads();               // everyone done reading sY
        if (w == 0) {
#pragma unroll
            for (int i = 0; i < 64; ++i) sY[lane * 68 + i] = y[i];
        }
        __syncthreads();
        for (int idx = tid; idx < 4096; idx += 256) {
            int jc = idx >> 6, i = idx & 63;
            LUT[(size_t)(jc0 + jc) * NMAT + k0 + i] = sY[jc * 68 + i];
        }
        return;
    }
    const int r0 = k1 + (blockIdx.y - 1) * 64;
    // prefetch C tile (independent of trsm -> overlaps)
    float acc[16];
#pragma unroll
    for (int rr = 0; rr < 16; ++rr)
        acc[rr] = LU[(size_t)(r0 + w * 16 + rr) * NMAT + jc0 + lane];
    trsm64_reg(y, sL);
    __syncthreads();                   // all waves done reading L11
    {
        const int i = tid >> 4, c4 = tid & 15;
        for (int rr = 0; rr < 64; rr += 16) {
            float4 v = *(const float4*)&LU[(size_t)(r0 + i + rr) * NMAT + k0 + 4 * c4];
            *(float4*)&sL[(i + rr) * 68 + 4 * c4] = v;   // L21
        }
    }
    __syncthreads();
#pragma unroll
    for (int kk = 0; kk < 64; ++kk) {
        float yk = y[kk];
#pragma unroll
        for (int rr = 0; rr < 16; ++rr)
            acc[rr] -= sL[(w * 16 + rr) * 68 + kk] * yk;
    }
#pragma unroll
    for (int rr = 0; rr < 16; ++rr)
        LU[(size_t)(r0 + w * 16 + rr) * NMAT + jc0 + lane] = acc[rr];
}

// ---------------- triangular solves, 12 RHS, 1 wave per RHS, coalesced column loads ----------
// mode 0: b = e_{500+c}, W = x (forward collapses to last diag block). mode 1: b = B[:,c], W += x.
__global__ void __launch_bounds__(64) k_solve(const float* __restrict__ LUT,
                                              const float* __restrict__ dinv,
                                              const float* __restrict__ B,
                                              float* __restrict__ W, int mode) {
    const int c = blockIdx.x;
    const int lane = threadIdx.x;
    float y[8];
    if (mode) {
#pragma unroll
        for (int s = 0; s < 8; ++s) y[s] = B[(s * 64 + lane) * MRHS + c];
#pragma unroll
        for (int js = 0; js < 8; ++js) {
#pragma unroll 4
            for (int jl = 0; jl < 64; ++jl) {
                const int j = js * 64 + jl;
                const float* __restrict__ col = &LUT[(size_t)j * NMAT];
                float yj = __shfl(y[js], jl);
                if (lane > jl) y[js] -= col[js * 64 + lane] * yj;
#pragma unroll
                for (int s = js + 1; s < 8; ++s) y[s] -= col[s * 64 + lane] * yj;
            }
        }
    } else {
#pragma unroll
        for (int s = 0; s < 8; ++s) y[s] = 0.f;
        y[7] = (lane == 52 + c) ? 1.0f : 0.0f;
        for (int jl = 52; jl < 63; ++jl) {
            const float* __restrict__ col = &LUT[(size_t)(448 + jl) * NMAT];
            float yj = __shfl(y[7], jl);
            if (lane > jl) y[7] -= col[448 + lane] * yj;
        }
    }
    // backward: U x = y
#pragma unroll
    for (int js = 7; js >= 0; --js) {
#pragma unroll 4
        for (int jl = 63; jl >= 0; --jl) {
            const int j = js * 64 + jl;
            const float* __restrict__ col = &LUT[(size_t)j * NMAT];
            float xj = __shfl(y[js], jl) * dinv[j];
            float t = y[js] - col[js * 64 + lane] * xj;
            y[js] = (lane < jl) ? t : ((lane == jl) ? xj : y[js]);
#pragma unroll
            for (int s = 0; s < js; ++s) y[s] -= col[s * 64 + lane] * xj;
        }
    }
#pragma unroll
    for (int s = 0; s < 8; ++s) {
        int row = s * 64 + lane;
        if (mode) W[row * MRHS + c] += y[s];
        else      W[row * MRHS + c] = y[s];
    }
}

// ---------------- residual R = I[:,500:512] - A @ W  (f64 accumulate) ----------------
__global__ void __launch_bounds__(64) k_resid(const float* __restrict__ A,
                                              const float* __restrict__ W,
                                              float* __restrict__ R) {
    const int row = blockIdx.x;
    const int lane = threadIdx.x;
    double acc[MRHS];
#pragma unroll
    for (int cc = 0; cc < MRHS; ++cc) acc[cc] = 0.0;
    for (int k = lane; k < NMAT; k += 64) {
        float a = A[(size_t)row * NMAT + k];
#pragma unroll
        for (int cc = 0; cc < MRHS; ++cc) acc[cc] += (double)a * (double)W[k * MRHS + cc];
    }
#pragma unroll
    for (int cc = 0; cc < MRHS; ++cc) {
        double v = acc[cc];
#pragma unroll
        for (int off = 32; off > 0; off >>= 1) v += __shfl_xor(v, off);
        if (lane == cc) R[row * MRHS + cc] = (float)(((row == 500 + cc) ? 1.0 : 0.0) - v);
    }
}

// ---------------- out[i][p] = sum_k W[i][k] * e[k][p] ----------------
__global__ void __launch_bounds__(256) k_out(const float* __restrict__ W,
                                             const float* __restrict__ x,
                                             float* __restrict__ out) {
    const int p4 = blockIdx.x * 256 + threadIdx.x;  // 0..1023
    const int i = blockIdx.y;
    const float4* __restrict__ x4 = (const float4*)x;
    float ax = 0.f, ay = 0.f, az = 0.f, aw = 0.f;
#pragma unroll
    for (int k = 0; k < MRHS; ++k) {
        float w = W[i * MRHS + k];
        float4 v = x4[k * 1024 + p4];
        ax += w * v.x; ay += w * v.y; az += w * v.z; aw += w * v.w;
    }
    float4 o; o.x = ax; o.y = ay; o.z = az; o.w = aw;
    ((float4*)out)[(size_t)i * 1024 + p4] = o;
}

extern "C" void kernel_launch(void* const* d_in, const int* in_sizes, int n_in,
                              void* d_out, int out_size, void* d_ws, size_t ws_size,
                              hipStream_t stream) {
    (void)in_sizes; (void)n_in; (void)out_size; (void)ws_size;
    const float* M     = (const float*)d_in[0];
    const float* r     = (const float*)d_in[1];
    const float* cpart = (const float*)d_in[2];
    const float* x     = (const float*)d_in[3];
    float* out = (float*)d_out;
    float* ws  = (float*)d_ws;

    float* LU   = ws;                 // 262144
    float* A    = ws + 262144;        // 262144
    float* LUT  = ws + 524288;        // 262144
    float* W    = ws + 786432;        // 6144
    float* R    = ws + 792576;        // 6144
    float* dinv = ws + 798720;        // 512

    // Stage 1: A = LU = constant_part + sum_e r[e] M[e]  (single fused kernel)
    k_setup<<<dim3(512), 256, 0, stream>>>(M, r, cpart, A, LU);

    // Stage 2: blocked LU (no pivoting), NB = 64.
    // Panel (writes LU + LUT-transposed panel + dinv) + fused register-trsm/gemm update
    // (y==0 blocks write U12^T straight into LUT; LU upper stays original A12 -> race-free).
    for (int p = 0; p < 8; ++p) {
        const int k0 = p * 64;
        switch (p) {
            case 0: k_panel<512><<<1, 1024, 0, stream>>>(LU, LUT, dinv, k0); break;
            case 1: k_panel<448><<<1, 1024, 0, stream>>>(LU, LUT, dinv, k0); break;
            case 2: k_panel<384><<<1, 1024, 0, stream>>>(LU, LUT, dinv, k0); break;
            case 3: k_panel<320><<<1, 1024, 0, stream>>>(LU, LUT, dinv, k0); break;
            case 4: k_panel<256><<<1, 1024, 0, stream>>>(LU, LUT, dinv, k0); break;
            case 5: k_panel<192><<<1, 1024, 0, stream>>>(LU, LUT, dinv, k0); break;
            case 6: k_panel<128><<<1, 1024, 0, stream>>>(LU, LUT, dinv, k0); break;
            case 7: k_panel< 64><<<1, 1024, 0, stream>>>(LU, LUT, dinv, k0); break;
        }
        const int nc = NMAT - k0 - 64;
        if (nc > 0)
            k_update<<<dim3(nc / 64, nc / 64 + 1), 256, 0, stream>>>(LU, LUT, k0);
    }

    // Stage 3: W = A^{-1} I[:,500:512], + 2 iterative-refinement steps
    k_solve<<<dim3(MRHS), 64, 0, stream>>>(LUT, dinv, R /*unused*/, W, 0);
    for (int it = 0; it < 2; ++it) {
        k_resid<<<dim3(NMAT), 64, 0, stream>>>(A, W, R);
        k_solve<<<dim3(MRHS), 64, 0, stream>>>(LUT, dinv, R, W, 1);
    }

    // Stage 4: out = W @ e
    k_out<<<dim3(4, 512), 256, 0, stream>>>(W, x, out);
}